// Round 4
// baseline (195.012 us; speedup 1.0000x reference)
//
#include <hip/hip_runtime.h>
#include <hip/hip_bf16.h>
#include <math.h>

#define NP_N 4096
#define NH_N 4096
#define D_N 512
#define BERT_N 768
#define H_N 4
#define B_N 32

typedef __attribute__((ext_vector_type(8))) short short8;
typedef __attribute__((ext_vector_type(4))) float f32x4;
typedef __attribute__((ext_vector_type(4))) unsigned short ush4;
typedef unsigned short ushort_t;

__device__ __forceinline__ void gl_lds16(const void* g, void* l) {
    __builtin_amdgcn_global_load_lds((const __attribute__((address_space(1))) void*)g,
                                     (__attribute__((address_space(3))) void*)l, 16, 0, 0);
}
__device__ __forceinline__ unsigned short f2bu(float f) {
    __hip_bfloat16 b = __float2bfloat16(f);
    return *reinterpret_cast<unsigned short*>(&b);
}
__device__ __forceinline__ float b2f(unsigned short u) {
    union { unsigned int i; float f; } x; x.i = ((unsigned int)u) << 16; return x.f;
}
__device__ __forceinline__ unsigned int pkbf(float a, float b) {
    union { __hip_bfloat162 h; unsigned int u; } x;
    x.h.x = __float2bfloat16(a);
    x.h.y = __float2bfloat16(b);
    return x.u;
}

// =========================== convert + transpose ===========================
#define EW_BLOCKS 512
__global__ __launch_bounds__(256) void convert_all(
    const float* __restrict__ ctx_h, const float* __restrict__ ctx_p,
    const float* __restrict__ lhs_p,
    const float* __restrict__ Wq, const float* __restrict__ Wk,
    const float* __restrict__ Wv, const float* __restrict__ W1,
    const float* __restrict__ bq, const float* __restrict__ bk,
    ushort_t* __restrict__ ctxp_bf, ushort_t* __restrict__ lhsp_bf,
    ushort_t* __restrict__ feats,
    ushort_t* __restrict__ Wqt, ushort_t* __restrict__ Wkt,
    ushort_t* __restrict__ Wvt, ushort_t* __restrict__ W1t,
    float* __restrict__ bqp, float* __restrict__ bkp)
{
    const int bid = blockIdx.x, t = threadIdx.x;
    if (bid < EW_BLOCKS) {
        const long N0 = 524288, N1 = 1048576, TOT = 1835008;  // float4 counts
        for (long i = (long)bid * 256 + t; i < TOT; i += (long)EW_BLOCKS * 256) {
            float4 v; ush4 o;
            if (i < N0) {
                long k = i;
                v = ((const float4*)ctx_h)[k];
                o[0] = f2bu(v.x); o[1] = f2bu(v.y); o[2] = f2bu(v.z); o[3] = f2bu(v.w);
                long n = k >> 7, c4 = k & 127;
                ((ush4*)feats)[n * 320 + c4] = o;      // feats[:, 0:512]
            } else if (i < N1) {
                long k = i - N0;
                v = ((const float4*)ctx_p)[k];
                o[0] = f2bu(v.x); o[1] = f2bu(v.y); o[2] = f2bu(v.z); o[3] = f2bu(v.w);
                ((ush4*)ctxp_bf)[k] = o;
            } else {
                long k = i - N1;
                v = ((const float4*)lhs_p)[k];
                o[0] = f2bu(v.x); o[1] = f2bu(v.y); o[2] = f2bu(v.z); o[3] = f2bu(v.w);
                ((ush4*)lhsp_bf)[k] = o;
            }
        }
        if (bid == 0) {
            for (int n = t; n < 512; n += 256) {
                int np = (n & 3) * 128 + (n >> 2);
                bqp[np] = bq[n];
                bkp[np] = bk[n];
            }
        }
        return;
    }
    // 64x64 weight transposes
    int tb = bid - EW_BLOCKS;
    const float* src; ushort_t* dst; int K, N, tile, perm;
    if (tb < 64)       { src = Wq; dst = Wqt; K = 512;  N = 512; tile = tb;       perm = 1; }
    else if (tb < 128) { src = Wk; dst = Wkt; K = 512;  N = 512; tile = tb - 64;  perm = 1; }
    else if (tb < 272) { src = Wv; dst = Wvt; K = 768;  N = 768; tile = tb - 128; perm = 0; }
    else               { src = W1; dst = W1t; K = 1280; N = 256; tile = tb - 272; perm = 0; }
    int ntn = N >> 6;
    int k0 = (tile / ntn) * 64, n0 = (tile % ntn) * 64;
    __shared__ float tl[64][65];
#pragma unroll
    for (int i = 0; i < 16; i++) {
        int idx = t + i * 256; int r = idx >> 6, c = idx & 63;
        tl[r][c] = src[(size_t)(k0 + r) * N + n0 + c];
    }
    __syncthreads();
#pragma unroll
    for (int i = 0; i < 16; i++) {
        int idx = t + i * 256; int r = idx >> 6, c = idx & 63;
        int n = n0 + r;
        int nr = perm ? ((n & 3) * 128 + (n >> 2)) : n;
        dst[(size_t)nr * K + k0 + c] = f2bu(tl[c][r]);
    }
}

// =========================== bf16 MFMA GEMM =================================
// C[m][n] = sum_k A[m][k] * Bt[n][k] (+bias, opt GELU), bf16 out. A has lda.
template<int BIAS_ROW, int GELU>
__global__ __launch_bounds__(256) void gemm_bf(
    const ushort_t* __restrict__ A, int lda, const ushort_t* __restrict__ Bt,
    const float* __restrict__ bias, ushort_t* __restrict__ C,
    int M, int N, int K)
{
    __shared__ ushort_t As[2][64 * 64];
    __shared__ ushort_t Bs[2][64 * 64];
    const int t = threadIdx.x, w = t >> 6, lane = t & 63;
    const int lq = lane & 15, g = lane >> 4;
    const int wm = w >> 1, wn = w & 1;
    const int n0 = blockIdx.x * 64, m0 = blockIdx.y * 64;
    const int nsteps = K >> 6;

    f32x4 acc[2][2];
#pragma unroll
    for (int a = 0; a < 2; a++)
#pragma unroll
        for (int b = 0; b < 2; b++) acc[a][b] = (f32x4){0.f, 0.f, 0.f, 0.f};

    auto STAGE = [&](int buf, int k0) {
#pragma unroll
        for (int jj = 0; jj < 2; jj++) {
            int j = w * 2 + jj;
            int r = j * 8 + (lane >> 3);
            int c = (lane & 7) * 16;
            int cs = c ^ ((r & 7) << 4);
            gl_lds16((const char*)A + ((size_t)(m0 + r) * lda + k0) * 2 + cs, (void*)&As[buf][j * 512]);
            gl_lds16((const char*)Bt + ((size_t)(n0 + r) * K + k0) * 2 + cs, (void*)&Bs[buf][j * 512]);
        }
    };

    STAGE(0, 0);
    __syncthreads();
    int cur = 0;
    for (int s = 0; s < nsteps; s++) {
        if (s + 1 < nsteps) STAGE(cur ^ 1, (s + 1) * 64);
        const char* Ab = (const char*)&As[cur][0];
        const char* Bb = (const char*)&Bs[cur][0];
        const int swz = (lq & 7) << 4;
        short8 af[2][2], bf[2][2];
#pragma unroll
        for (int mf = 0; mf < 2; mf++) {
            int r = wm * 32 + mf * 16 + lq;
#pragma unroll
            for (int ks = 0; ks < 2; ks++)
                af[mf][ks] = *(const short8*)(Ab + r * 128 + ((ks * 64 + g * 16) ^ swz));
        }
#pragma unroll
        for (int nf = 0; nf < 2; nf++) {
            int r = wn * 32 + nf * 16 + lq;
#pragma unroll
            for (int ks = 0; ks < 2; ks++)
                bf[nf][ks] = *(const short8*)(Bb + r * 128 + ((ks * 64 + g * 16) ^ swz));
        }
#pragma unroll
        for (int mf = 0; mf < 2; mf++)
#pragma unroll
            for (int nf = 0; nf < 2; nf++)
#pragma unroll
                for (int ks = 0; ks < 2; ks++)
                    acc[mf][nf] = __builtin_amdgcn_mfma_f32_16x16x32_bf16(
                        af[mf][ks], bf[nf][ks], acc[mf][nf], 0, 0, 0);
        __syncthreads();
        cur ^= 1;
    }

#pragma unroll
    for (int mf = 0; mf < 2; mf++) {
#pragma unroll
        for (int nf = 0; nf < 2; nf++) {
            int ncol = n0 + wn * 32 + nf * 16 + lq;
            float bcol = BIAS_ROW ? 0.f : bias[ncol];
#pragma unroll
            for (int j = 0; j < 4; j++) {
                int mrow = m0 + wm * 32 + mf * 16 + 4 * g + j;
                float v = acc[mf][nf][j] + (BIAS_ROW ? bias[mrow] : bcol);
                if (GELU) v = 0.5f * v * (1.f + erff(v * 0.70710678118654752f));
                C[(size_t)mrow * N + ncol] = f2bu(v);
            }
        }
    }
}

// =========================== MFMA flash attention ===========================
// grid 256: (bid&7) -> (head h = (bid&7)>>1, outer key-split s = bid&1);
// qblk = bid>>3 (32 of them), 128 queries per block.
// Block: 512 thr = 8 waves; quads o=w>>2 each own an independent 1024-key
// stream with private double-buffered K/V LDS (160KB total). Wave owns 32
// queries (2 fragment groups sharing every LDS read). P is staged through the
// retiring K buffer. exp2-domain online softmax with defer-max (THR=8).
// In-block merge of the two streams; stores unnormalized O (bf16) + (m,l).
__global__ __launch_bounds__(512, 2) void attn_mfma(
    const ushort_t* __restrict__ Qb,   // [4096][512] cols = h*128+d
    const ushort_t* __restrict__ Kb,   // [4096][512]
    const ushort_t* __restrict__ Vtb,  // [768][4096] rows = h*192+vd
    const int* __restrict__ batch_h, const int* __restrict__ batch_p,
    ushort_t* __restrict__ Opart,      // [2][4][4096][192]
    float* __restrict__ ml)            // [2][4][4096][2]
{
    const int bid = blockIdx.x;
    const int h = (bid & 7) >> 1;
    const int s = bid & 1;
    const int n0 = (bid >> 3) * 128;

    __shared__ __align__(16) char smem[163840];

    const int t = threadIdx.x;
    const int w = t >> 6, o = w >> 2, wq = w & 3;
    const int lane = t & 63, lq = lane & 15, g = lane >> 4;
    const int lqm = (lq & 7) << 4;
    const float scl2 = 0.12754245006257576f;   // log2(e)/sqrt(128)

    char* Kt0 = smem + (o * 2 + 0) * 16384;    // [64][128] bf16, 16KB
    char* Kt1 = smem + (o * 2 + 1) * 16384;
    char* Vt0 = smem + 65536 + (o * 2 + 0) * 24576;  // [192][64] bf16, 24KB
    char* Vt1 = smem + 65536 + (o * 2 + 1) * 24576;

    // Q fragments: queries n0 + wq*32 + qg*16 + lq
    short8 qf[2][4];
    int bhq[2];
#pragma unroll
    for (int qg = 0; qg < 2; qg++) {
        const ushort_t* qrow = Qb + (size_t)(n0 + wq * 32 + qg * 16 + lq) * 512 + h * 128;
#pragma unroll
        for (int ks = 0; ks < 4; ks++)
            qf[qg][ks] = *(const short8*)(qrow + ks * 32 + g * 8);
        bhq[qg] = batch_h[n0 + wq * 32 + qg * 16 + lq];
    }

    f32x4 Ofr[2][12];
#pragma unroll
    for (int qg = 0; qg < 2; qg++)
#pragma unroll
        for (int nt = 0; nt < 12; nt++) Ofr[qg][nt] = (f32x4){0.f, 0.f, 0.f, 0.f};
    float m_run[2] = {-1e30f, -1e30f}, l_run[2] = {0.f, 0.f};

    const char* Kg = (const char*)Kb;
    const char* Vg = (const char*)Vtb;
    const int kb = s * 2048 + o * 1024;

    auto STAGE = [&](char* Kd, char* Vd, int m0k) {
#pragma unroll
        for (int jj = 0; jj < 4; jj++) {              // K: 16 instrs / quad
            int j = wq * 4 + jj;
            int r = j * 4 + (lane >> 4);
            int c = (lane & 15) * 16;
            gl_lds16(Kg + (size_t)(m0k + r) * 1024 + h * 256 + (c ^ ((r & 7) << 4)),
                     Kd + j * 1024);
        }
#pragma unroll
        for (int jj = 0; jj < 6; jj++) {              // V: 24 instrs / quad
            int j = wq * 6 + jj;
            int r = j * 8 + (lane >> 3);
            int c = (lane & 7) * 16;
            gl_lds16(Vg + ((size_t)(h * 192 + r) * 4096 + m0k) * 2 + (c ^ ((r & 7) << 4)),
                     Vd + j * 1024);
        }
    };

    STAGE(Kt0, Vt0, kb);
    __syncthreads();
    int cur = 0;

    for (int tile = 0; tile < 16; tile++) {
        char* Kc = cur ? Kt1 : Kt0;
        char* Vc = cur ? Vt1 : Vt0;
        if (tile + 1 < 16) STAGE(cur ? Kt0 : Kt1, cur ? Vt0 : Vt1, kb + (tile + 1) * 64);

        // ---- S^T = K·Q^T, both query groups share every kf read ----
        f32x4 S[2][4];
#pragma unroll
        for (int qg = 0; qg < 2; qg++)
#pragma unroll
            for (int mt = 0; mt < 4; mt++) S[qg][mt] = (f32x4){0.f, 0.f, 0.f, 0.f};
#pragma unroll
        for (int mt = 0; mt < 4; mt++) {
            const char* rbase = Kc + (mt * 16 + lq) * 256;
#pragma unroll
            for (int ks = 0; ks < 4; ks++) {
                short8 kf = *(const short8*)(rbase + ((ks * 64 + g * 16) ^ lqm));
                S[0][mt] = __builtin_amdgcn_mfma_f32_16x16x32_bf16(kf, qf[0][ks], S[0][mt], 0, 0, 0);
                S[1][mt] = __builtin_amdgcn_mfma_f32_16x16x32_bf16(kf, qf[1][ks], S[1][mt], 0, 0, 0);
            }
        }

        // ---- mask + scale (log2 domain) + online softmax ----
        int4 bp4[4];
#pragma unroll
        for (int mt = 0; mt < 4; mt++)
            bp4[mt] = *(const int4*)&batch_p[kb + tile * 64 + mt * 16 + 4 * g];

        float mx[2];
#pragma unroll
        for (int qg = 0; qg < 2; qg++) {
            float m = -1e30f;
#pragma unroll
            for (int mt = 0; mt < 4; mt++) {
                float v0 = (bp4[mt].x == bhq[qg]) ? -1e9f : S[qg][mt][0] * scl2;
                float v1 = (bp4[mt].y == bhq[qg]) ? -1e9f : S[qg][mt][1] * scl2;
                float v2 = (bp4[mt].z == bhq[qg]) ? -1e9f : S[qg][mt][2] * scl2;
                float v3 = (bp4[mt].w == bhq[qg]) ? -1e9f : S[qg][mt][3] * scl2;
                S[qg][mt][0] = v0; S[qg][mt][1] = v1; S[qg][mt][2] = v2; S[qg][mt][3] = v3;
                m = fmaxf(m, fmaxf(fmaxf(v0, v1), fmaxf(v2, v3)));
            }
            m = fmaxf(m, __shfl_xor(m, 16));
            m = fmaxf(m, __shfl_xor(m, 32));
            mx[qg] = m;
        }
        bool ng = __all((mx[0] <= m_run[0] + 8.f) && (mx[1] <= m_run[1] + 8.f));

        uint2 P2[2][4];
#pragma unroll
        for (int qg = 0; qg < 2; qg++) {
            float m_new = ng ? m_run[qg] : fmaxf(m_run[qg], mx[qg]);
            float rsum = 0.f;
#pragma unroll
            for (int mt = 0; mt < 4; mt++) {
                float e0 = exp2f(S[qg][mt][0] - m_new);
                float e1 = exp2f(S[qg][mt][1] - m_new);
                float e2 = exp2f(S[qg][mt][2] - m_new);
                float e3 = exp2f(S[qg][mt][3] - m_new);
                rsum += (e0 + e1) + (e2 + e3);
                P2[qg][mt].x = pkbf(e0, e1);
                P2[qg][mt].y = pkbf(e2, e3);
            }
            rsum += __shfl_xor(rsum, 16);
            rsum += __shfl_xor(rsum, 32);
            if (ng) {
                l_run[qg] += rsum;
            } else {
                float f = exp2f(m_run[qg] - m_new);
                l_run[qg] = l_run[qg] * f + rsum;
                m_run[qg] = m_new;
                float fr0 = __shfl(f, 4 * g + 0);
                float fr1 = __shfl(f, 4 * g + 1);
                float fr2 = __shfl(f, 4 * g + 2);
                float fr3 = __shfl(f, 4 * g + 3);
#pragma unroll
                for (int nt = 0; nt < 12; nt++) {
                    Ofr[qg][nt][0] *= fr0; Ofr[qg][nt][1] *= fr1;
                    Ofr[qg][nt][2] *= fr2; Ofr[qg][nt][3] *= fr3;
                }
            }
        }

        __syncthreads();   // quad done reading K fragments from Kc

        // ---- stage P into retiring K buffer (wave-private 4KB) ----
        char* Pz = Kc + wq * 4096;
#pragma unroll
        for (int qg = 0; qg < 2; qg++)
#pragma unroll
            for (int mt = 0; mt < 4; mt++)
                *(uint2*)(Pz + qg * 2048 + lq * 128 + ((mt * 32 + g * 8) ^ lqm)) = P2[qg][mt];

        // ---- O += P·V, both groups share every vf read ----
#pragma unroll
        for (int ks = 0; ks < 2; ks++) {
            short8 pf0 = *(const short8*)(Pz + 0 * 2048 + lq * 128 + ((ks * 64 + g * 16) ^ lqm));
            short8 pf1 = *(const short8*)(Pz + 1 * 2048 + lq * 128 + ((ks * 64 + g * 16) ^ lqm));
#pragma unroll
            for (int nt = 0; nt < 12; nt++) {
                short8 vf = *(const short8*)(Vc + (nt * 16 + lq) * 128 + ((ks * 64 + g * 16) ^ lqm));
                Ofr[0][nt] = __builtin_amdgcn_mfma_f32_16x16x32_bf16(pf0, vf, Ofr[0][nt], 0, 0, 0);
                Ofr[1][nt] = __builtin_amdgcn_mfma_f32_16x16x32_bf16(pf1, vf, Ofr[1][nt], 0, 0, 0);
            }
        }

        __syncthreads();   // PV + P reads done before next tile overwrites
        cur ^= 1;
    }

    // ---- in-block merge of the two key streams ----
    const int tq = wq * 64 + lane;                 // 0..255 within quad
    float* mOf = (float*)smem;                     // [256][96]
    float* mls = (float*)(smem + 98304);           // [64][4]
    if (o == 1) {
#pragma unroll
        for (int qg = 0; qg < 2; qg++) {
#pragma unroll
            for (int nt = 0; nt < 12; nt++)
                *(f32x4*)(mOf + tq * 96 + qg * 48 + nt * 4) = Ofr[qg][nt];
            if (g == 0) {
                mls[(wq * 16 + lq) * 4 + qg * 2 + 0] = m_run[qg];
                mls[(wq * 16 + lq) * 4 + qg * 2 + 1] = l_run[qg];
            }
        }
    }
    __syncthreads();
    if (o == 0) {
        const size_t plane = (size_t)(s * 4 + h) * 4096;
#pragma unroll
        for (int qg = 0; qg < 2; qg++) {
            float m1 = mls[(wq * 16 + lq) * 4 + qg * 2 + 0];
            float l1 = mls[(wq * 16 + lq) * 4 + qg * 2 + 1];
            float m = fmaxf(m_run[qg], m1);
            float a0 = exp2f(m_run[qg] - m), a1 = exp2f(m1 - m);
            float l = l_run[qg] * a0 + l1 * a1;
            int qrow = n0 + wq * 32 + qg * 16;
            if (g == 0) {
                ml[(plane + qrow + lq) * 2 + 0] = m;
                ml[(plane + qrow + lq) * 2 + 1] = l;
            }
            float f0[4], f1[4];
#pragma unroll
            for (int j = 0; j < 4; j++) {
                f0[j] = __shfl(a0, 4 * g + j);
                f1[j] = __shfl(a1, 4 * g + j);
            }
#pragma unroll
            for (int nt = 0; nt < 12; nt++) {
                f32x4 o1 = *(f32x4*)(mOf + tq * 96 + qg * 48 + nt * 4);
#pragma unroll
                for (int j = 0; j < 4; j++) {
                    float val = Ofr[qg][nt][j] * f0[j] + o1[j] * f1[j];
                    Opart[(plane + qrow + 4 * g + j) * 192 + nt * 16 + lq] = f2bu(val);
                }
            }
        }
    }
}

// ============== combine outer key-split + build feats tail ==============
__global__ __launch_bounds__(256) void combine_feats(
    const ushort_t* __restrict__ Opart, const float* __restrict__ ml,
    const float* __restrict__ lhs_h, ushort_t* __restrict__ feats)
{
    const int t = threadIdx.x;
#pragma unroll
    for (int i = 0; i < 4; i++) {
        int q = blockIdx.x * 4 + i;
#pragma unroll
        for (int it = 0; it < 3; it++) {
            int c = t + it * 256;
            int h = c / 192, vd = c - h * 192;
            size_t i0 = (size_t)h * 4096 + q;
            size_t i1 = (size_t)(4 + h) * 4096 + q;
            float m0 = ml[i0 * 2], l0 = ml[i0 * 2 + 1];
            float m1 = ml[i1 * 2], l1 = ml[i1 * 2 + 1];
            float m = fmaxf(m0, m1);
            float e0 = exp2f(m0 - m), e1 = exp2f(m1 - m);
            float linv = 1.f / (l0 * e0 + l1 * e1);
            float O = (b2f(Opart[i0 * 192 + vd]) * e0 + b2f(Opart[i1 * 192 + vd]) * e1) * linv;
            feats[(size_t)q * 1280 + 512 + c] = f2bu(lhs_h[(size_t)q * 768 + c] - O);
        }
    }
}

// ================= h2 = h1 @ W2 (f32) + LayerNorm(128) ======================
__global__ __launch_bounds__(256) void h2_ln(
    const ushort_t* __restrict__ h1, const float* __restrict__ W2,
    const float* __restrict__ ln_g, const float* __restrict__ ln_b,
    float* __restrict__ h2out)
{
    const int n0 = blockIdx.x * 8;
    const int t = threadIdx.x;
    __shared__ float h1s[8][256];
    __shared__ float h2s[8][128];

#pragma unroll
    for (int i = 0; i < 8; i++) {
        int idx = t + i * 256; int r = idx >> 8, c = idx & 255;
        h1s[r][c] = b2f(h1[(size_t)(n0 + r) * 256 + c]);
    }
    __syncthreads();

    {
        int o2 = t & 127, gq = t >> 7;
        float acc[4] = {};
        for (int k4 = 0; k4 < 64; k4++) {
            float w0 = W2[(size_t)(k4 * 4 + 0) * 128 + o2];
            float w1 = W2[(size_t)(k4 * 4 + 1) * 128 + o2];
            float w2 = W2[(size_t)(k4 * 4 + 2) * 128 + o2];
            float w3 = W2[(size_t)(k4 * 4 + 3) * 128 + o2];
#pragma unroll
            for (int q = 0; q < 4; q++) {
                float4 hh = *(const float4*)&h1s[gq * 4 + q][k4 * 4];
                acc[q] += hh.x * w0 + hh.y * w1 + hh.z * w2 + hh.w * w3;
            }
        }
#pragma unroll
        for (int q = 0; q < 4; q++) h2s[gq * 4 + q][o2] = acc[q];
    }
    __syncthreads();

    {
        int wv = t >> 6, lane = t & 63;
#pragma unroll
        for (int sx = 0; sx < 2; sx++) {
            int nd = wv * 2 + sx;
            float x0 = h2s[nd][lane], x1 = h2s[nd][lane + 64];
            float sum = x0 + x1;
#pragma unroll
            for (int off = 32; off; off >>= 1) sum += __shfl_xor(sum, off);
            float mu = sum * (1.f / 128.f);
            float d0 = x0 - mu, d1 = x1 - mu;
            float s2 = d0 * d0 + d1 * d1;
#pragma unroll
            for (int off = 32; off; off >>= 1) s2 += __shfl_xor(s2, off);
            float rstd = rsqrtf(s2 * (1.f / 128.f) + 1e-5f);
            size_t base = (size_t)(n0 + nd) * 128;
            h2out[base + lane]      = d0 * rstd * ln_g[lane] + ln_b[lane];
            h2out[base + lane + 64] = d1 * rstd * ln_g[lane + 64] + ln_b[lane + 64];
        }
    }
}

// ----------------------- segment ranges (batch ids sorted) -----------------
__global__ void ranges_kernel(const int* __restrict__ bh, int* __restrict__ lo,
                              int Nn, int Bn)
{
    int n = blockIdx.x * blockDim.x + threadIdx.x;
    if (n >= Nn) return;
    int b = bh[n];
    int prev = (n == 0) ? -1 : bh[n - 1];
    for (int bb = prev + 1; bb <= b; bb++) lo[bb] = n;
    if (n == Nn - 1) for (int bb = b + 1; bb <= Bn; bb++) lo[bb] = Nn;
}

// ----------------------- pool (mean per graph) + classifier ----------------
__global__ __launch_bounds__(128) void pool_cls(
    const float* __restrict__ h2, const int* __restrict__ lo,
    const float* __restrict__ Wc, const float* __restrict__ bc,
    float* __restrict__ out)
{
    int b = blockIdx.x, t = threadIdx.x;
    int s = lo[b], e = lo[b + 1];
    float acc = 0.f;
    for (int n = s; n < e; n++) acc += h2[(size_t)n * 128 + t];
    float pooled = acc / fmaxf((float)(e - s), 1.f);
    __shared__ float red[128];
    for (int c = 0; c < 3; c++) {
        red[t] = pooled * Wc[t * 3 + c];
        __syncthreads();
        for (int off = 64; off > 0; off >>= 1) {
            if (t < off) red[t] += red[t + off];
            __syncthreads();
        }
        if (t == 0) out[b * 3 + c] = red[0] + bc[c];
        __syncthreads();
    }
}

// ---------------------------------------------------------------------------
extern "C" void kernel_launch(void* const* d_in, const int* in_sizes, int n_in,
                              void* d_out, int out_size, void* d_ws, size_t ws_size,
                              hipStream_t stream)
{
    const float* ctx_p  = (const float*)d_in[0];
    const float* ctx_h  = (const float*)d_in[1];
    const float* lhs_p  = (const float*)d_in[2];
    const float* lhs_h  = (const float*)d_in[3];
    const int*   batch_p = (const int*)d_in[4];
    const int*   batch_h = (const int*)d_in[5];
    const float* Wq = (const float*)d_in[6];
    const float* bq = (const float*)d_in[7];
    const float* Wk = (const float*)d_in[8];
    const float* bk = (const float*)d_in[9];
    const float* Wv = (const float*)d_in[10];
    const float* bv = (const float*)d_in[11];
    const float* W1 = (const float*)d_in[12];
    const float* b1 = (const float*)d_in[13];
    const float* W2 = (const float*)d_in[14];
    const float* ln_g = (const float*)d_in[15];
    const float* ln_b = (const float*)d_in[16];
    const float* Wc = (const float*)d_in[17];
    const float* bc = (const float*)d_in[18];
    float* out = (float*)d_out;

    // ---- workspace layout (ushort units unless noted) ----
    ushort_t* u = (ushort_t*)d_ws;
    ushort_t* ctxp_bf = u;                         // 2097152
    ushort_t* lhsp_bf = ctxp_bf + 2097152;         // 3145728
    ushort_t* Wqt  = lhsp_bf + 3145728;            // 262144
    ushort_t* Wkt  = Wqt + 262144;                 // 262144
    ushort_t* Wvt  = Wkt + 262144;                 // 589824
    ushort_t* Opart = u;                           // ALIAS: 6291456 over [ctxp..Wvt]
    ushort_t* W1t  = Wvt + 589824;                 // 327680
    ushort_t* Qb   = W1t + 327680;                 // 2097152
    ushort_t* Kb   = Qb + 2097152;                 // 2097152
    ushort_t* Vtb  = Kb + 2097152;                 // 3145728
    ushort_t* feats = Vtb + 3145728;               // 5242880
    ushort_t* h1   = feats + 5242880;              // 1048576
    float* ml  = (float*)(h1 + 1048576);           // 65536 f32
    float* h2  = ml + 65536;                       // 524288 f32
    float* bqp = h2 + 524288;                      // 512
    float* bkp = bqp + 512;                        // 512
    int*   lo  = (int*)(bkp + 512);                // 33

    convert_all<<<864, 256, 0, stream>>>(
        ctx_h, ctx_p, lhs_p, Wq, Wk, Wv, W1, bq, bk,
        ctxp_bf, lhsp_bf, feats, Wqt, Wkt, Wvt, W1t, bqp, bkp);

    gemm_bf<0, 0><<<dim3(8, 64), 256, 0, stream>>>(feats, 1280, Wqt, bqp, Qb, NH_N, 512, 512);
    gemm_bf<0, 0><<<dim3(8, 64), 256, 0, stream>>>(ctxp_bf, 512, Wkt, bkp, Kb, NP_N, 512, 512);
    gemm_bf<1, 0><<<dim3(64, 12), 256, 0, stream>>>(Wvt, 768, lhsp_bf, bv, Vtb, 768, NP_N, 768);

    attn_mfma<<<256, 512, 0, stream>>>(Qb, Kb, Vtb, batch_h, batch_p, Opart, ml);

    combine_feats<<<1024, 256, 0, stream>>>(Opart, ml, lhs_h, feats);

    gemm_bf<0, 1><<<dim3(4, 64), 256, 0, stream>>>(feats, 1280, W1t, b1, h1, NH_N, 256, 1280);

    h2_ln<<<512, 256, 0, stream>>>(h1, W2, ln_g, ln_b, h2);
    ranges_kernel<<<16, 256, 0, stream>>>(batch_h, lo, NH_N, B_N);
    pool_cls<<<B_N, 128, 0, stream>>>(h2, lo, Wc, bc, out);
}